// Round 3
// baseline (106.514 us; speedup 1.0000x reference)
//
#include <hip/hip_runtime.h>
#include <math.h>

#define B_SZ   256
#define T_SZ   50
#define N_OBS  8192
#define N_KC   50

using f32x4 = __attribute__((ext_vector_type(4))) float;

// Persistent cross-launch barrier counter (module global: NOT poisoned by the
// harness). The barrier protocol is modular/wrap-safe and needs no reset:
// each block waits until (ctr - my_old) >= (256 - my_old%256), i.e. until all
// 256 blocks of THIS launch have arrived, regardless of the starting value.
__device__ unsigned int g_ctr = 0;

// Broadcast lane l's float to all lanes as a wave-uniform value via
// v_readlane (no LDS traffic, no lgkmcnt).
__device__ __forceinline__ float rlf(float v, int l) {
    return __uint_as_float((unsigned)__builtin_amdgcn_readlane((int)__float_as_uint(v), l));
}

// ---------------------------------------------------------------------------
// Fused kernel: one 512-thread block per batch element (256 blocks = 1/CU,
// all co-resident -> manual global barrier is deadlock-free).
//
// Phase 1 (all blocks, ~1 us):
//   - issue scan-input loads (prev_kc/curr_kc/prev_corr), cold HBM
//   - distributed one-hot scan: block b converts its 400-float4 slice of A
//     into assign8 bytes in workspace (the old K1, now inlined)
//   - sigmoid(kc_logits) -> LDS
//   - argmax over A rows pk/ck -> s_kakc: gives the scan its ka/kc WITHOUT
//     depending on other blocks' assign8 slices
// Barrier (overlapped): wave7/lane63 does agent-release atomicAdd + spin
//   WHILE wave 0 runs the serial scan -> barrier wait costs ~0.
// Phase 2: expand state_out[b][j] = s_state[assign8[j]] (needs the global
//   barrier: assign8 was written by all blocks).
// ---------------------------------------------------------------------------
__global__ void __launch_bounds__(512) k_fused(
        const int*   __restrict__ prev_kc,
        const int*   __restrict__ curr_kc,
        const float* __restrict__ prev_corr,
        const float* __restrict__ A,
        const float* __restrict__ kc_logits,
        unsigned char* __restrict__ assign8,   // workspace, 8 KB
        float* __restrict__ probs_out,         // [B][T]
        float* __restrict__ state_out) {       // [B][N_OBS]
    const int b    = blockIdx.x;
    const int tid  = threadIdx.x;        // 0..511
    const int lane = tid & 63;
    const int wave = tid >> 6;

    __shared__ float s_probs[N_KC * 5 + 6];
    __shared__ float s_state[64];
    __shared__ unsigned char s_kakc[2 * T_SZ];  // [0..49]=ka, [50..99]=kc

    // (1) Scan-input loads first (HBM-cold after the workspace poison).
    int pk = 0, ck = 0;
    float corr = 0.0f;
    if (tid < T_SZ) {
        pk   = prev_kc[b * T_SZ + tid];
        corr = prev_corr[b * T_SZ + tid];
    } else if (tid < 2 * T_SZ) {
        ck = curr_kc[b * T_SZ + (tid - T_SZ)];
    }

    // (2) Distributed one-hot scan (old K1): 102400 float4 / 256 blocks = 400
    //     per block; threads 0..399 take one float4 each. Block b writes
    //     assign8[b*32 .. b*32+32) (32 one-hot rows per 1600-float slice).
    if (tid < 400) {
        const int idx = b * 400 + tid;
        const float4 v = ((const float4*)A)[idx];
        const int e = idx * 4;
        if (v.x > 0.5f) assign8[(e + 0) / N_KC] = (unsigned char)((e + 0) % N_KC);
        if (v.y > 0.5f) assign8[(e + 1) / N_KC] = (unsigned char)((e + 1) % N_KC);
        if (v.z > 0.5f) assign8[(e + 2) / N_KC] = (unsigned char)((e + 2) % N_KC);
        if (v.w > 0.5f) assign8[(e + 3) / N_KC] = (unsigned char)((e + 3) % N_KC);
    }

    // (3) Sigmoid table.
    for (int i = tid; i < N_KC * 5; i += 512) {
        float x = kc_logits[i];
        s_probs[i] = __builtin_amdgcn_rcpf(1.0f + __expf(-x));
    }

    // (4) Own-row argmax: scan's ka/kc from A directly (no assign8 dep).
    //     100 threads x 50 scalar loads (~25 KB/block, mostly IF$-warm since
    //     phase 2's chunk loads stream all of A concurrently).
    if (tid < 2 * T_SZ) {
        const int row = (tid < T_SZ) ? pk : ck;
        const float* rp = A + row * N_KC;
        int idx = 0;
        #pragma unroll
        for (int i = 0; i < N_KC; ++i) {
            float v = rp[i];
            idx = (v > 0.5f) ? i : idx;
        }
        s_kakc[tid] = (unsigned char)idx;
    }

    // Drains vmcnt(0) per wave: this block's assign8 stores are complete in
    // the local L2 before wave 7 releases; s_probs/s_kakc visible block-wide.
    __syncthreads();

    if (wave == 0) {
        // ---- Serial scan (identical math to R2; ka/kc from s_kakc). ----
        const bool scanlane = lane < T_SZ;
        int ka = 0, kc = 0;
        if (scanlane) {
            ka = s_kakc[lane];
            kc = s_kakc[T_SZ + lane];
        }
        float po0 = 0.f, dp = 0.f, cfp1 = 0.f, pl = 0.f, c2 = 0.f, dc = 0.f;
        if (scanlane) {
            float pp0 = s_probs[ka * 5 + 0];
            float pp1 = s_probs[ka * 5 + 1];
            float pp2 = s_probs[ka * 5 + 2];
            float pp3 = s_probs[ka * 5 + 3];
            bool c = corr > 0.5f;
            po0 = c ? pp2 : 1.0f - pp2;
            float po1 = c ? pp3 : 1.0f - pp3;
            dp   = po1 - po0;
            pl   = pp0;
            cfp1 = (1.0f - pp1 - pp0) * po1;
            c2   = s_probs[kc * 5 + 2];
            dc   = s_probs[kc * 5 + 3] - c2;
        }

        float st = (lane < N_KC) ? s_probs[lane * 5 + 4] : 0.0f;
        float pc_mine = 0.0f;

        // t = 0: prediction only.
        {
            int   kc0 = __builtin_amdgcn_readlane(kc, 0);
            float cs  = rlf(st, kc0);
            float pc  = __builtin_fmaf(rlf(dc, 0), cs, rlf(c2, 0));
            if (lane == 0) pc_mine = pc;
        }

        // t = 1..T-1: pure-VALU carried chain fma -> rcp -> fma -> cndmask;
        // all broadcasts via readlane (immediates after full unroll).
        #pragma unroll
        for (int t = 1; t < T_SZ; ++t) {
            int   ka_t   = __builtin_amdgcn_readlane(ka, t);
            float po0_t  = rlf(po0, t);
            float dp_t   = rlf(dp, t);
            float cfp1_t = rlf(cfp1, t);
            float pl_t   = rlf(pl, t);
            int   kc_t   = __builtin_amdgcn_readlane(kc, t);
            float c2_t   = rlf(c2, t);
            float dc_t   = rlf(dc, t);

            float ss   = st;
            float t1   = cfp1_t * ss;                       // off-chain
            float den  = __builtin_fmaf(dp_t, ss, po0_t);
            float pred = __builtin_fmaf(t1, __builtin_amdgcn_rcpf(den), pl_t);
            if (lane == ka_t) st = pred;

            float cs = rlf(st, kc_t);
            float pc = __builtin_fmaf(dc_t, cs, c2_t);
            if (lane == t) pc_mine = pc;
        }

        if (scanlane) probs_out[b * T_SZ + lane] = pc_mine;
        s_state[lane] = st;
    } else if (tid == 511) {
        // ---- Global barrier arrival + wait, concurrent with the scan. ----
        // Agent-release: flushes this XCD's L2 (incl. peers' assign8 stores,
        // already drained by the __syncthreads above) before the add lands.
        unsigned old = __hip_atomic_fetch_add(&g_ctr, 1u, __ATOMIC_RELEASE,
                                              __HIP_MEMORY_SCOPE_AGENT);
        unsigned need = 256u - (old & 255u);   // arrivals still missing
        while ((unsigned)(__hip_atomic_load(&g_ctr, __ATOMIC_ACQUIRE,
                                            __HIP_MEMORY_SCOPE_AGENT) - old) < need)
            __builtin_amdgcn_s_sleep(1);
    }
    __syncthreads();      // joins: scan done AND all 256 blocks arrived
    __threadfence();      // invalidate stale lines before reading assign8

    // Phase 2 — expand: state_out[b][j] = s_state[assign[j]].
    const unsigned int* a32 = (const unsigned int*)assign8;
    unsigned int pa[4];
    #pragma unroll
    for (int k = 0; k < 4; ++k) pa[k] = a32[tid + k * 512];

    f32x4* outp = (f32x4*)(state_out + (long)b * N_OBS);
    #pragma unroll
    for (int k = 0; k < 4; ++k) {
        const int i = tid + k * 512;
        const unsigned int w = pa[k];
        f32x4 v;
        v.x = s_state[w & 0xffu];
        v.y = s_state[(w >> 8)  & 0xffu];
        v.z = s_state[(w >> 16) & 0xffu];
        v.w = s_state[(w >> 24) & 0xffu];
        __builtin_nontemporal_store(v, &outp[i]);
    }
}

extern "C" void kernel_launch(void* const* d_in, const int* in_sizes, int n_in,
                              void* d_out, int out_size, void* d_ws, size_t ws_size,
                              hipStream_t stream) {
    const int*   prev_kc   = (const int*)  d_in[0];
    const int*   curr_kc   = (const int*)  d_in[1];
    const float* prev_corr = (const float*)d_in[2];
    const float* kc_logits = (const float*)d_in[3];
    const float* A         = (const float*)d_in[4];

    float* probs_out = (float*)d_out;                 // B*T
    float* state_out = (float*)d_out + B_SZ * T_SZ;   // B*N_OBS

    unsigned char* assign8 = (unsigned char*)d_ws;    // 8 KB of workspace

    k_fused<<<B_SZ, 512, 0, stream>>>(prev_kc, curr_kc, prev_corr, A,
                                      kc_logits, assign8,
                                      probs_out, state_out);
}

// Round 4
// 75.646 us; speedup vs baseline: 1.4081x; 1.4081x over previous
//
#include <hip/hip_runtime.h>
#include <math.h>

#define B_SZ   256
#define T_SZ   50
#define N_OBS  8192
#define N_KC   50

using f32x4 = __attribute__((ext_vector_type(4))) float;

// Persistent cross-launch barrier counter (module global: NOT poisoned by the
// harness). Modular/wrap-safe, needs no reset: each block waits until
// (ctr - my_old) >= (256 - my_old%256), i.e. until all 256 blocks of THIS
// launch have arrived, regardless of the starting value.
__device__ unsigned int g_ctr = 0;

// Broadcast lane l's float to all lanes as a wave-uniform value via
// v_readlane (no LDS traffic, no lgkmcnt).
__device__ __forceinline__ float rlf(float v, int l) {
    return __uint_as_float((unsigned)__builtin_amdgcn_readlane((int)__float_as_uint(v), l));
}

// ---------------------------------------------------------------------------
// Fused kernel: one 512-thread block per batch element (256 blocks = 1/CU,
// all co-resident -> manual global barrier is deadlock-free).
//
// Barrier coherence at BLOCK granularity (the R3 lesson):
//   release: ONE RELEASE fetch_add per block (one L2 writeback) -- all the
//     block's assign8 stores are already in L2 (write-through L1 + the
//     vmcnt(0) the compiler emits before s_barrier).
//   poll:    RELAXED agent loads (sc1 -> reads the LLC, observes remote
//     arrivals, emits NO cache maintenance per iteration).
//   acquire: ONE fence(acquire,"agent") by the spinning thread after the
//     spin exits -- invalidates this CU's L1 + this XCD's L2 once; all 8
//     waves of the block share exactly those caches, so block-wide reads of
//     assign8 after __syncthreads are current. No per-thread threadfence.
// ---------------------------------------------------------------------------
__global__ void __launch_bounds__(512) k_fused(
        const int*   __restrict__ prev_kc,
        const int*   __restrict__ curr_kc,
        const float* __restrict__ prev_corr,
        const float* __restrict__ A,
        const float* __restrict__ kc_logits,
        unsigned char* __restrict__ assign8,   // workspace, 8 KB
        float* __restrict__ probs_out,         // [B][T]
        float* __restrict__ state_out) {       // [B][N_OBS]
    const int b    = blockIdx.x;
    const int tid  = threadIdx.x;        // 0..511
    const int lane = tid & 63;
    const int wave = tid >> 6;

    __shared__ float s_probs[N_KC * 5 + 6];
    __shared__ float s_state[64];
    __shared__ unsigned char s_kakc[2 * T_SZ];  // [0..49]=ka, [50..99]=kc

    // (1) Scan-input loads first (HBM-cold after the workspace poison).
    int pk = 0, ck = 0;
    float corr = 0.0f;
    if (tid < T_SZ) {
        pk   = prev_kc[b * T_SZ + tid];
        corr = prev_corr[b * T_SZ + tid];
    } else if (tid < 2 * T_SZ) {
        ck = curr_kc[b * T_SZ + (tid - T_SZ)];
    }

    // (2) Distributed one-hot scan (old K1): 102400 float4 / 256 blocks = 400
    //     per block; threads 0..399 take one float4 each. Block b writes
    //     assign8[b*32 .. b*32+32).
    if (tid < 400) {
        const int idx = b * 400 + tid;
        const float4 v = ((const float4*)A)[idx];
        const int e = idx * 4;
        if (v.x > 0.5f) assign8[(e + 0) / N_KC] = (unsigned char)((e + 0) % N_KC);
        if (v.y > 0.5f) assign8[(e + 1) / N_KC] = (unsigned char)((e + 1) % N_KC);
        if (v.z > 0.5f) assign8[(e + 2) / N_KC] = (unsigned char)((e + 2) % N_KC);
        if (v.w > 0.5f) assign8[(e + 3) / N_KC] = (unsigned char)((e + 3) % N_KC);
    }

    // (3) Sigmoid table.
    for (int i = tid; i < N_KC * 5; i += 512) {
        float x = kc_logits[i];
        s_probs[i] = __builtin_amdgcn_rcpf(1.0f + __expf(-x));
    }

    // (4) Own-row argmax: scan's ka/kc straight from A (no cross-block dep).
    if (tid < 2 * T_SZ) {
        const int row = (tid < T_SZ) ? pk : ck;
        const float* rp = A + row * N_KC;
        int idx = 0;
        #pragma unroll
        for (int i = 0; i < N_KC; ++i) {
            float v = rp[i];
            idx = (v > 0.5f) ? i : idx;
        }
        s_kakc[tid] = (unsigned char)idx;
    }

    // Per-wave vmcnt(0) before s_barrier: all assign8 stores are in L2
    // (L1 is write-through) when any wave passes this point.
    __syncthreads();

    if (wave == 0) {
        // ---- Serial scan (identical math to R2; ka/kc from s_kakc). ----
        const bool scanlane = lane < T_SZ;
        int ka = 0, kc = 0;
        if (scanlane) {
            ka = s_kakc[lane];
            kc = s_kakc[T_SZ + lane];
        }
        float po0 = 0.f, dp = 0.f, cfp1 = 0.f, pl = 0.f, c2 = 0.f, dc = 0.f;
        if (scanlane) {
            float pp0 = s_probs[ka * 5 + 0];
            float pp1 = s_probs[ka * 5 + 1];
            float pp2 = s_probs[ka * 5 + 2];
            float pp3 = s_probs[ka * 5 + 3];
            bool c = corr > 0.5f;
            po0 = c ? pp2 : 1.0f - pp2;
            float po1 = c ? pp3 : 1.0f - pp3;
            dp   = po1 - po0;
            pl   = pp0;
            cfp1 = (1.0f - pp1 - pp0) * po1;
            c2   = s_probs[kc * 5 + 2];
            dc   = s_probs[kc * 5 + 3] - c2;
        }

        float st = (lane < N_KC) ? s_probs[lane * 5 + 4] : 0.0f;
        float pc_mine = 0.0f;

        // t = 0: prediction only.
        {
            int   kc0 = __builtin_amdgcn_readlane(kc, 0);
            float cs  = rlf(st, kc0);
            float pc  = __builtin_fmaf(rlf(dc, 0), cs, rlf(c2, 0));
            if (lane == 0) pc_mine = pc;
        }

        // t = 1..T-1: pure-VALU carried chain fma -> rcp -> fma -> cndmask;
        // all broadcasts via readlane (immediates after full unroll).
        #pragma unroll
        for (int t = 1; t < T_SZ; ++t) {
            int   ka_t   = __builtin_amdgcn_readlane(ka, t);
            float po0_t  = rlf(po0, t);
            float dp_t   = rlf(dp, t);
            float cfp1_t = rlf(cfp1, t);
            float pl_t   = rlf(pl, t);
            int   kc_t   = __builtin_amdgcn_readlane(kc, t);
            float c2_t   = rlf(c2, t);
            float dc_t   = rlf(dc, t);

            float ss   = st;
            float t1   = cfp1_t * ss;                       // off-chain
            float den  = __builtin_fmaf(dp_t, ss, po0_t);
            float pred = __builtin_fmaf(t1, __builtin_amdgcn_rcpf(den), pl_t);
            if (lane == ka_t) st = pred;

            float cs = rlf(st, kc_t);
            float pc = __builtin_fmaf(dc_t, cs, c2_t);
            if (lane == t) pc_mine = pc;
        }

        if (scanlane) probs_out[b * T_SZ + lane] = pc_mine;
        s_state[lane] = st;
    } else if (tid == 511) {
        // ---- Global barrier, concurrent with the scan. ----
        // RELEASE add: one L2 writeback -> this block's assign8 bytes reach
        // the LLC before our arrival is visible to anyone.
        unsigned old = __hip_atomic_fetch_add(&g_ctr, 1u, __ATOMIC_RELEASE,
                                              __HIP_MEMORY_SCOPE_AGENT);
        unsigned need = 256u - (old & 255u);   // arrivals still missing
        // RELAXED polls: sc1 load straight from the LLC, no cache
        // maintenance per iteration (the R3 mistake was ACQUIRE here).
        while ((unsigned)(__hip_atomic_load(&g_ctr, __ATOMIC_RELAXED,
                                            __HIP_MEMORY_SCOPE_AGENT) - old) < need)
            __builtin_amdgcn_s_sleep(16);
        // ONE acquire fence per block: invalidates this CU's L1 and this
        // XCD's L2 -- sufficient for every wave of this block.
        __builtin_amdgcn_fence(__ATOMIC_ACQUIRE, "agent");
    }
    __syncthreads();      // joins: scan done AND all 256 blocks arrived

    // Phase 2 — expand: state_out[b][j] = s_state[assign[j]].
    const unsigned int* a32 = (const unsigned int*)assign8;
    unsigned int pa[4];
    #pragma unroll
    for (int k = 0; k < 4; ++k) pa[k] = a32[tid + k * 512];

    f32x4* outp = (f32x4*)(state_out + (long)b * N_OBS);
    #pragma unroll
    for (int k = 0; k < 4; ++k) {
        const int i = tid + k * 512;
        const unsigned int w = pa[k];
        f32x4 v;
        v.x = s_state[w & 0xffu];
        v.y = s_state[(w >> 8)  & 0xffu];
        v.z = s_state[(w >> 16) & 0xffu];
        v.w = s_state[(w >> 24) & 0xffu];
        __builtin_nontemporal_store(v, &outp[i]);
    }
}

extern "C" void kernel_launch(void* const* d_in, const int* in_sizes, int n_in,
                              void* d_out, int out_size, void* d_ws, size_t ws_size,
                              hipStream_t stream) {
    const int*   prev_kc   = (const int*)  d_in[0];
    const int*   curr_kc   = (const int*)  d_in[1];
    const float* prev_corr = (const float*)d_in[2];
    const float* kc_logits = (const float*)d_in[3];
    const float* A         = (const float*)d_in[4];

    float* probs_out = (float*)d_out;                 // B*T
    float* state_out = (float*)d_out + B_SZ * T_SZ;   // B*N_OBS

    unsigned char* assign8 = (unsigned char*)d_ws;    // 8 KB of workspace

    k_fused<<<B_SZ, 512, 0, stream>>>(prev_kc, curr_kc, prev_corr, A,
                                      kc_logits, assign8,
                                      probs_out, state_out);
}

// Round 5
// 70.371 us; speedup vs baseline: 1.5136x; 1.0749x over previous
//
#include <hip/hip_runtime.h>
#include <math.h>

#define B_SZ   256
#define T_SZ   50
#define N_OBS  8192
#define N_KC   50

using f32x4 = __attribute__((ext_vector_type(4))) float;

// Broadcast lane l's float to all lanes as a wave-uniform value via
// v_readlane (no LDS traffic, no lgkmcnt).
__device__ __forceinline__ float rlf(float v, int l) {
    return __uint_as_float((unsigned)__builtin_amdgcn_readlane((int)__float_as_uint(v), l));
}

// ---------------------------------------------------------------------------
// K1: blocks 0..399: assign8[i] = one-hot column of A row i (the R2 kernel,
//     unchanged). Blocks 400..407: LLC-prefetch of K2's entry inputs
//     (prev_kc/curr_kc/prev_corr/kc_logits, ~154 KB). The Infinity Cache is
//     memory-side, so these discarded reads warm it for K2, whose entry
//     loads gate the serial scan. asm sink keeps the loads live (DCE guard).
// ---------------------------------------------------------------------------
__global__ void __launch_bounds__(256) k_assign(
        const float* __restrict__ A,
        unsigned char* __restrict__ assign8,
        const float* __restrict__ prev_kc,
        const float* __restrict__ curr_kc,
        const float* __restrict__ prev_corr,
        const float* __restrict__ kc_logits) {
    if (blockIdx.x < 400) {
        const int idx = blockIdx.x * 256 + threadIdx.x;   // float4 index
        // N_OBS*N_KC = 409600 floats = 102400 float4 -> exactly 400 blocks.
        const float4 v = ((const float4*)A)[idx];
        const int e = idx * 4;
        if (v.x > 0.5f) assign8[(e + 0) / N_KC] = (unsigned char)((e + 0) % N_KC);
        if (v.y > 0.5f) assign8[(e + 1) / N_KC] = (unsigned char)((e + 1) % N_KC);
        if (v.z > 0.5f) assign8[(e + 2) / N_KC] = (unsigned char)((e + 2) % N_KC);
        if (v.w > 0.5f) assign8[(e + 3) / N_KC] = (unsigned char)((e + 3) % N_KC);
    } else {
        // 8 blocks x 256 threads prefetch 3 x 3200 float4 + 250 floats.
        const int t = (blockIdx.x - 400) * 256 + threadIdx.x;   // 0..2047
        float s = 0.0f;
        #pragma unroll
        for (int k = 0; k < 2; ++k) {
            const int i = t + k * 2048;
            if (i < 3200) {   // B*T ints = 12800 dwords = 3200 float4
                float4 a = ((const float4*)prev_kc)[i];
                float4 b = ((const float4*)curr_kc)[i];
                float4 c = ((const float4*)prev_corr)[i];
                s += a.x + a.y + a.z + a.w
                   + b.x + b.y + b.z + b.w
                   + c.x + c.y + c.z + c.w;
            }
        }
        if (t < N_KC * 5) s += kc_logits[t];
        asm volatile("" :: "v"(s));   // keep prefetch loads live
    }
}

// ---------------------------------------------------------------------------
// K2: one 512-thread block per batch element, fused scan + expand.
//     (R2 kernel, byte-for-byte: measured 69.9 us total.)
//     Scan (wave 0): pure-VALU serial recurrence; carried chain is
//     fma -> rcp -> fma -> cndmask; all broadcasts via v_readlane; T-loop
//     fully unrolled. Entry loads now LLC-warm thanks to K1's prefetch.
// ---------------------------------------------------------------------------
__global__ void __launch_bounds__(512) k_scan_expand(
        const int*   __restrict__ prev_kc,
        const int*   __restrict__ curr_kc,
        const float* __restrict__ prev_corr,
        const unsigned char* __restrict__ assign8,
        const float* __restrict__ kc_logits,
        float* __restrict__ probs_out,    // [B][T]
        float* __restrict__ state_out) {  // [B][N_OBS]
    const int b    = blockIdx.x;
    const int tid  = threadIdx.x;        // 0..511
    const int lane = tid & 63;
    const int wave = tid >> 6;

    __shared__ float s_probs[N_KC * 5 + 6];
    __shared__ float s_state[64];

    // Issue the scan's input loads FIRST; they complete behind the sigmoid.
    const bool scanlane = (wave == 0) && (lane < T_SZ);
    int pk = 0, ck = 0;
    float corr = 0.0f;
    if (scanlane) {
        pk   = prev_kc[b * T_SZ + lane];
        ck   = curr_kc[b * T_SZ + lane];
        corr = prev_corr[b * T_SZ + lane];
    }

    for (int i = tid; i < N_KC * 5; i += 512) {
        float x = kc_logits[i];
        s_probs[i] = __builtin_amdgcn_rcpf(1.0f + __expf(-x));
    }

    // Dependent gathers: issue as soon as pk/ck are back.
    int ka = 0, kc = 0;
    if (scanlane) {
        ka = assign8[pk];
        kc = assign8[ck];
    }

    // Prefetch this thread's expand indices: 4 dwords, each packing 4 uint8
    // assign values; independent of the scan, complete behind it.
    const unsigned int* a32 = (const unsigned int*)assign8;
    unsigned int pa[4];
    #pragma unroll
    for (int k = 0; k < 4; ++k) pa[k] = a32[tid + k * 512];

    __syncthreads();

    if (wave == 0) {
        // Per-step constants: lane t (t < T) holds the values for timestep t.
        float po0 = 0.f, dp = 0.f, cfp1 = 0.f, pl = 0.f, c2 = 0.f, dc = 0.f;
        if (scanlane) {
            float pp0 = s_probs[ka * 5 + 0];
            float pp1 = s_probs[ka * 5 + 1];
            float pp2 = s_probs[ka * 5 + 2];
            float pp3 = s_probs[ka * 5 + 3];
            bool c = corr > 0.5f;
            po0 = c ? pp2 : 1.0f - pp2;
            float po1 = c ? pp3 : 1.0f - pp3;
            dp   = po1 - po0;
            pl   = pp0;
            cfp1 = (1.0f - pp1 - pp0) * po1;
            c2   = s_probs[kc * 5 + 2];
            dc   = s_probs[kc * 5 + 3] - c2;
        }

        // Initial per-KC state: lane k holds sigmoid(kc_logits[k,4]).
        float st = (lane < N_KC) ? s_probs[lane * 5 + 4] : 0.0f;

        float pc_mine = 0.0f;

        // t = 0: prediction only, no state update.
        {
            int   kc0 = __builtin_amdgcn_readlane(kc, 0);
            float cs  = rlf(st, kc0);
            float pc  = __builtin_fmaf(rlf(dc, 0), cs, rlf(c2, 0));
            if (lane == 0) pc_mine = pc;
        }

        // t = 1..T-1: serial recurrence, fully unrolled.
        #pragma unroll
        for (int t = 1; t < T_SZ; ++t) {
            int   ka_t   = __builtin_amdgcn_readlane(ka, t);
            float po0_t  = rlf(po0, t);
            float dp_t   = rlf(dp, t);
            float cfp1_t = rlf(cfp1, t);
            float pl_t   = rlf(pl, t);
            int   kc_t   = __builtin_amdgcn_readlane(kc, t);
            float c2_t   = rlf(c2, t);
            float dc_t   = rlf(dc, t);

            // Local update: lane ka_t owns state[ka_t]; no cross-lane op.
            float ss   = st;
            float t1   = cfp1_t * ss;                       // off-chain
            float den  = __builtin_fmaf(dp_t, ss, po0_t);
            float pred = __builtin_fmaf(t1, __builtin_amdgcn_rcpf(den), pl_t);
            if (lane == ka_t) st = pred;

            // Prediction gather: kc_t is wave-uniform -> readlane, no DS.
            float cs = rlf(st, kc_t);
            float pc = __builtin_fmaf(dc_t, cs, c2_t);
            if (lane == t) pc_mine = pc;
        }

        if (lane < T_SZ) probs_out[b * T_SZ + lane] = pc_mine;
        s_state[lane] = st;
    }
    __syncthreads();

    // Expand: state_out[b][j] = s_state[assign[j]].
    f32x4* outp = (f32x4*)(state_out + (long)b * N_OBS);
    #pragma unroll
    for (int k = 0; k < 4; ++k) {
        const int i = tid + k * 512;
        const unsigned int w = pa[k];
        f32x4 v;
        v.x = s_state[w & 0xffu];
        v.y = s_state[(w >> 8)  & 0xffu];
        v.z = s_state[(w >> 16) & 0xffu];
        v.w = s_state[(w >> 24) & 0xffu];
        __builtin_nontemporal_store(v, &outp[i]);
    }
}

extern "C" void kernel_launch(void* const* d_in, const int* in_sizes, int n_in,
                              void* d_out, int out_size, void* d_ws, size_t ws_size,
                              hipStream_t stream) {
    const int*   prev_kc   = (const int*)  d_in[0];
    const int*   curr_kc   = (const int*)  d_in[1];
    const float* prev_corr = (const float*)d_in[2];
    const float* kc_logits = (const float*)d_in[3];
    const float* A         = (const float*)d_in[4];

    float* probs_out = (float*)d_out;                 // B*T
    float* state_out = (float*)d_out + B_SZ * T_SZ;   // B*N_OBS

    unsigned char* assign8 = (unsigned char*)d_ws;    // 8 KB of workspace

    // 400 one-hot blocks + 8 prefetch blocks.
    k_assign<<<408, 256, 0, stream>>>(A, assign8,
                                      (const float*)prev_kc,
                                      (const float*)curr_kc,
                                      prev_corr, kc_logits);
    k_scan_expand<<<B_SZ, 512, 0, stream>>>(prev_kc, curr_kc, prev_corr,
                                            assign8, kc_logits,
                                            probs_out, state_out);
}

// Round 6
// 69.864 us; speedup vs baseline: 1.5246x; 1.0073x over previous
//
#include <hip/hip_runtime.h>
#include <math.h>

#define B_SZ   256
#define T_SZ   50
#define N_OBS  8192
#define N_KC   50

using f32x4 = __attribute__((ext_vector_type(4))) float;

// Broadcast lane l's float to all lanes as a wave-uniform value via
// v_readlane (no LDS traffic, no lgkmcnt).
__device__ __forceinline__ float rlf(float v, int l) {
    return __uint_as_float((unsigned)__builtin_amdgcn_readlane((int)__float_as_uint(v), l));
}

// ---------------------------------------------------------------------------
// K1: assign8[i] = column of the single 1.0 in one-hot row A[i,:], as uint8
//     (N_KC=50 < 256). A is scanned FLAT with float4 (fully coalesced,
//     1.6 MB); each one-hot hit produces one scattered byte store.
//     This full-A pass is the one structurally-forced pass: the scan needs
//     assign[] at arbitrary rows, so the table must be globally visible
//     before K2 (kernel boundary = cheapest coherence, measured R3/R4).
// ---------------------------------------------------------------------------
__global__ void __launch_bounds__(256) k_assign(
        const float* __restrict__ A,
        unsigned char* __restrict__ assign8) {
    const int idx = blockIdx.x * 256 + threadIdx.x;   // float4 index
    // N_OBS*N_KC = 409600 floats = 102400 float4 -> exactly 400 blocks.
    const float4 v = ((const float4*)A)[idx];
    const int e = idx * 4;
    if (v.x > 0.5f) assign8[(e + 0) / N_KC] = (unsigned char)((e + 0) % N_KC);
    if (v.y > 0.5f) assign8[(e + 1) / N_KC] = (unsigned char)((e + 1) % N_KC);
    if (v.z > 0.5f) assign8[(e + 2) / N_KC] = (unsigned char)((e + 2) % N_KC);
    if (v.w > 0.5f) assign8[(e + 3) / N_KC] = (unsigned char)((e + 3) % N_KC);
}

// ---------------------------------------------------------------------------
// K2: one 512-thread block per batch element, fused scan + expand.
//     Scan (wave 0): pure-VALU serial recurrence. The state update at step t
//     touches ONLY state[ka_t], owned by lane ka_t -> carried chain is
//     den=fma -> rcp -> fma -> cndmask (~20 cy/step, no cross-lane op).
//     ALL broadcasts, including the post-update gather cs = state[kc_t],
//     use v_readlane (kc_t is wave-uniform) -> zero DS ops in the scan.
//     T-loop fully unrolled so next-step readlanes schedule under this
//     step's chain. Input loads issued at kernel entry to overlap their
//     latency with the sigmoid/LDS phase.
// ---------------------------------------------------------------------------
__global__ void __launch_bounds__(512) k_scan_expand(
        const int*   __restrict__ prev_kc,
        const int*   __restrict__ curr_kc,
        const float* __restrict__ prev_corr,
        const unsigned char* __restrict__ assign8,
        const float* __restrict__ kc_logits,
        float* __restrict__ probs_out,    // [B][T]
        float* __restrict__ state_out) {  // [B][N_OBS]
    const int b    = blockIdx.x;
    const int tid  = threadIdx.x;        // 0..511
    const int lane = tid & 63;
    const int wave = tid >> 6;

    __shared__ float s_probs[N_KC * 5 + 6];
    __shared__ float s_state[64];

    // Issue the scan's input loads FIRST; they complete behind the sigmoid.
    const bool scanlane = (wave == 0) && (lane < T_SZ);
    int pk = 0, ck = 0;
    float corr = 0.0f;
    if (scanlane) {
        pk   = prev_kc[b * T_SZ + lane];
        ck   = curr_kc[b * T_SZ + lane];
        corr = prev_corr[b * T_SZ + lane];
    }

    for (int i = tid; i < N_KC * 5; i += 512) {
        float x = kc_logits[i];
        s_probs[i] = __builtin_amdgcn_rcpf(1.0f + __expf(-x));
    }

    // Dependent gathers: issue as soon as pk/ck are back.
    int ka = 0, kc = 0;
    if (scanlane) {
        ka = assign8[pk];
        kc = assign8[ck];
    }

    // Prefetch this thread's expand indices: 4 dwords, each packing 4 uint8
    // assign values; independent of the scan, complete behind it.
    const unsigned int* a32 = (const unsigned int*)assign8;
    unsigned int pa[4];
    #pragma unroll
    for (int k = 0; k < 4; ++k) pa[k] = a32[tid + k * 512];

    __syncthreads();

    if (wave == 0) {
        // Per-step constants: lane t (t < T) holds the values for timestep t.
        //   po0   : p_out[:,0]        (pow reduced to select, corr in {0,1})
        //   dp    : po1 - po0         (den = fma(dp, ss, po0))
        //   cfp1  : (1-pf-pl) * po1   (pred = fma(cfp1*ss, rcp(den), pl))
        //   pl    : p_learn
        //   c2/dc : cp2, cp3-cp2      (pc = fma(dc, cs, c2))
        float po0 = 0.f, dp = 0.f, cfp1 = 0.f, pl = 0.f, c2 = 0.f, dc = 0.f;
        if (scanlane) {
            float pp0 = s_probs[ka * 5 + 0];
            float pp1 = s_probs[ka * 5 + 1];
            float pp2 = s_probs[ka * 5 + 2];
            float pp3 = s_probs[ka * 5 + 3];
            bool c = corr > 0.5f;
            po0 = c ? pp2 : 1.0f - pp2;
            float po1 = c ? pp3 : 1.0f - pp3;
            dp   = po1 - po0;
            pl   = pp0;
            cfp1 = (1.0f - pp1 - pp0) * po1;
            c2   = s_probs[kc * 5 + 2];
            dc   = s_probs[kc * 5 + 3] - c2;
        }

        // Initial per-KC state: lane k holds sigmoid(kc_logits[k,4]).
        float st = (lane < N_KC) ? s_probs[lane * 5 + 4] : 0.0f;

        float pc_mine = 0.0f;

        // t = 0: prediction only, no state update.
        {
            int   kc0 = __builtin_amdgcn_readlane(kc, 0);
            float cs  = rlf(st, kc0);
            float pc  = __builtin_fmaf(rlf(dc, 0), cs, rlf(c2, 0));
            if (lane == 0) pc_mine = pc;
        }

        // t = 1..T-1: serial recurrence, fully unrolled (readlane lane
        // operands become immediates; independent broadcasts for step t+1
        // schedule under step t's fma->rcp->fma->cndmask chain).
        #pragma unroll
        for (int t = 1; t < T_SZ; ++t) {
            int   ka_t   = __builtin_amdgcn_readlane(ka, t);
            float po0_t  = rlf(po0, t);
            float dp_t   = rlf(dp, t);
            float cfp1_t = rlf(cfp1, t);
            float pl_t   = rlf(pl, t);
            int   kc_t   = __builtin_amdgcn_readlane(kc, t);
            float c2_t   = rlf(c2, t);
            float dc_t   = rlf(dc, t);

            // Local update: lane ka_t owns state[ka_t]; no cross-lane op.
            float ss   = st;
            float t1   = cfp1_t * ss;                       // off-chain
            float den  = __builtin_fmaf(dp_t, ss, po0_t);
            float pred = __builtin_fmaf(t1, __builtin_amdgcn_rcpf(den), pl_t);
            if (lane == ka_t) st = pred;

            // Prediction gather: kc_t is wave-uniform -> readlane, no DS.
            float cs = rlf(st, kc_t);
            float pc = __builtin_fmaf(dc_t, cs, c2_t);
            if (lane == t) pc_mine = pc;
        }

        if (lane < T_SZ) probs_out[b * T_SZ + lane] = pc_mine;
        s_state[lane] = st;
    }
    __syncthreads();

    // Expand: state_out[b][j] = s_state[assign[j]].
    // Unpack 4 uint8 indices per dword, LDS gather, coalesced float4 store.
    f32x4* outp = (f32x4*)(state_out + (long)b * N_OBS);
    #pragma unroll
    for (int k = 0; k < 4; ++k) {
        const int i = tid + k * 512;
        const unsigned int w = pa[k];
        f32x4 v;
        v.x = s_state[w & 0xffu];
        v.y = s_state[(w >> 8)  & 0xffu];
        v.z = s_state[(w >> 16) & 0xffu];
        v.w = s_state[(w >> 24) & 0xffu];
        __builtin_nontemporal_store(v, &outp[i]);
    }
}

extern "C" void kernel_launch(void* const* d_in, const int* in_sizes, int n_in,
                              void* d_out, int out_size, void* d_ws, size_t ws_size,
                              hipStream_t stream) {
    const int*   prev_kc   = (const int*)  d_in[0];
    const int*   curr_kc   = (const int*)  d_in[1];
    const float* prev_corr = (const float*)d_in[2];
    const float* kc_logits = (const float*)d_in[3];
    const float* A         = (const float*)d_in[4];

    float* probs_out = (float*)d_out;                 // B*T
    float* state_out = (float*)d_out + B_SZ * T_SZ;   // B*N_OBS

    unsigned char* assign8 = (unsigned char*)d_ws;    // 8 KB of workspace

    k_assign<<<(N_OBS * N_KC / 4) / 256, 256, 0, stream>>>(A, assign8);
    k_scan_expand<<<B_SZ, 512, 0, stream>>>(prev_kc, curr_kc, prev_corr,
                                            assign8, kc_logits,
                                            probs_out, state_out);
}